// Round 6
// baseline (135.084 us; speedup 1.0000x reference)
//
#include <hip/hip_runtime.h>
#include <math.h>

#define B_ 16
#define L_ 128
#define D_ 768
#define H1_ 770
#define OUT_ 40
#define NPAIRS 3405     // sum over i of min(30, 128-i)
#define NLOG 1540       // logical cols of Y: U(770) || V(770)
#define YSB 1552        // bf16 Y row stride in shorts (16B-aligned rows)
#define VOFFB 776       // V part at +776 shorts (1552 B, 16B-aligned)
#define KPAD 800        // 25 x 32 MFMA k-steps (k >= 770 zero-padded in B/Cv)
#define NPAD 48         // 40 outs padded to 3 x 16
#define W1TROWS 1600    // W1T rows padded (zeros in [1540,1600)) for safe staging
#define NTILES 252      // 4x4 (i,j) tiles covering the band
#define NKS 25

typedef __attribute__((ext_vector_type(8))) short bf16x8;
typedef __attribute__((ext_vector_type(8))) unsigned short u16x8;
typedef __attribute__((ext_vector_type(4))) float f32x4;
typedef __attribute__((ext_vector_type(4))) unsigned int u32x4;

__device__ inline unsigned short f2bf(float f) {
  unsigned int u = __builtin_bit_cast(unsigned int, f);
  u += 0x7fffu + ((u >> 16) & 1u);          // round-to-nearest-even
  return (unsigned short)(u >> 16);
}
__device__ inline float bf2f(unsigned short x) {
  return __builtin_bit_cast(float, (unsigned int)x << 16);
}

#if __has_builtin(__builtin_amdgcn_cvt_pk_bf16_f32)
typedef __attribute__((ext_vector_type(2))) __bf16 bf16x2_t;
__device__ inline unsigned int pack_bf16(float lo, float hi) {
  bf16x2_t r = __builtin_amdgcn_cvt_pk_bf16_f32(lo, hi);
  return __builtin_bit_cast(unsigned int, r);
}
#else
__device__ inline unsigned int pack_bf16(float lo, float hi) {
  return (unsigned int)f2bf(lo) | ((unsigned int)f2bf(hi) << 16);
}
#endif

// async global->LDS, 16B per lane; LDS dest = wave-uniform base + lane*16
typedef const __attribute__((address_space(1))) void* gas_t;
typedef __attribute__((address_space(3))) void* las_t;
__device__ inline void gl2lds16(const void* g, void* l) {
  __builtin_amdgcn_global_load_lds((gas_t)g, (las_t)l, 16, 0, 0);
}

// ---------------------------------------------------------------------------
// Kernel 0 (merged prep): block ranges —
//  [0,1536):        Xb[2048][768] = bf16(hidden rows, skipping CLS)
//  [1536,1696):     Bswz (W2 in MFMA B-frag order, zero-padded) + Cv
//  [1696,2896):     W1T[n][k] = bf16(W1'[k][n]), rows [1540,1600) zeroed
// ---------------------------------------------------------------------------
#define NB_X 1536      // 2048*192 elements / 256
#define NB_W 160       // 25*3*512 + 3*800 = 40800 elements
#define NB_T 1200      // 50 n-tiles x 24 k-tiles

__global__ __launch_bounds__(256) void prep_all(
    const float* __restrict__ hidden, const float* __restrict__ W1,
    const float* __restrict__ b1, const float* __restrict__ W2,
    unsigned short* __restrict__ Xb, unsigned short* __restrict__ W1T,
    unsigned short* __restrict__ Bswz, float* __restrict__ Cv)
{
  __shared__ float t[32][33];
  int bx = blockIdx.x;
  const int tid = threadIdx.x;

  if (bx < NB_X) {                       // ---- X convert ----
    int idx = bx * 256 + tid;
    int m = idx / 192;
    int c = idx - m * 192;
    float4 f = *(const float4*)(hidden + (size_t)(m + (m >> 7) + 1) * D_ + c * 4);
    ushort4 o;
    o.x = f2bf(f.x); o.y = f2bf(f.y); o.z = f2bf(f.z); o.w = f2bf(f.w);
    *(ushort4*)(Xb + (size_t)m * D_ + c * 4) = o;
    return;
  }
  bx -= NB_X;
  if (bx < NB_W) {                       // ---- Bswz + Cv ----
    int idx = bx * 256 + tid;
    if (idx < NKS * 3 * 512) {
      int ks = idx / 1536;
      int rem = idx - ks * 1536;
      int f = rem / 512;
      int l = (rem - f * 512) >> 3;
      int e = rem & 7;
      int n = f * 16 + (l & 15);
      int k = ks * 32 + (l >> 4) * 8 + e;
      float v = (n < OUT_ && k < H1_) ? W2[k * OUT_ + n] : 0.f;
      Bswz[idx] = f2bf(v);
    } else if (idx < NKS * 3 * 512 + 3 * KPAD) {
      int c = idx - NKS * 3 * 512;
      int tt = c / KPAD, k = c - tt * KPAD;
      const float* w1c = W1 + 1536 * H1_;
      Cv[c] = (k < H1_) ? (b1[k] + (float)tt * w1c[k]) : 0.f;
    }
    return;
  }
  bx -= NB_W;                            // ---- W1T transpose ----
  const int tx = tid & 31, ty = tid >> 5;
  const int n0 = (bx % 50) * 32, k0 = (bx / 50) * 32;
  #pragma unroll
  for (int r = 0; r < 4; ++r) {
    int k = k0 + ty + r * 8, n = n0 + tx;
    float v = 0.f;
    if (n < H1_)       v = W1[k * H1_ + n];
    else if (n < NLOG) v = W1[(D_ + k) * H1_ + (n - H1_)];
    t[ty + r * 8][tx] = v;
  }
  __syncthreads();
  #pragma unroll
  for (int r = 0; r < 4; ++r) {
    int n = n0 + ty + r * 8, k = k0 + tx;
    W1T[(size_t)n * D_ + k] = f2bf(t[tx][ty + r * 8]);   // n < 1600 always
  }
}

// ---------------------------------------------------------------------------
// Kernel 1 (MFMA, double-buffered async staging): Yb = Xb @ W1T^T (bf16 out)
// 64x64 tile, BK=64, 4 waves x (2x2 16x16x32 frags); prefetch chunk k+1 into
// the idle LDS buffer while chunk k's MFMAs run.
// ---------------------------------------------------------------------------
__global__ __launch_bounds__(256) void gemm1_mfma(
    const unsigned short* __restrict__ Xb, const unsigned short* __restrict__ W1T,
    unsigned short* __restrict__ Yb)
{
  __shared__ unsigned short As[2][64][64];   // 16 KB
  __shared__ unsigned short Bs[2][64][64];   // 16 KB
  const int tid = threadIdx.x;
  const int lane = tid & 63, w = tid >> 6;
  const int lm = lane & 15, q = lane >> 4;
  const int row0 = blockIdx.y * 64, col0 = blockIdx.x * 64;
  const int m0 = (w >> 1) * 32, n0 = (w & 1) * 32;

  // staging: wave w owns tile rows [w*16, w*16+16); lane l -> row +l/8, chunk l%8
  const int srow = w * 16 + (lane >> 3);
  const int schunk = (lane & 7) * 8;
  const unsigned short* ga = Xb  + (size_t)(row0 + srow) * D_ + schunk;
  const unsigned short* gb = W1T + (size_t)(col0 + srow) * D_ + schunk;

  f32x4 acc[2][2] = {};

  auto stage = [&](int k0, int b) {
    gl2lds16(ga + k0,          &As[b][w * 16][0]);
    gl2lds16(ga + k0 + 8 * D_, &As[b][w * 16 + 8][0]);
    gl2lds16(gb + k0,          &Bs[b][w * 16][0]);
    gl2lds16(gb + k0 + 8 * D_, &Bs[b][w * 16 + 8][0]);
  };

  stage(0, 0);
  for (int it = 0; it < 12; ++it) {
    const int cur = it & 1;
    __syncthreads();                    // drains chunk `it` into LDS[cur]
    if (it < 11) stage((it + 1) * 64, cur ^ 1);   // prefetch under compute
    #pragma unroll
    for (int ks = 0; ks < 2; ++ks) {
      bf16x8 a0 = *(const bf16x8*)&As[cur][m0 + lm]     [ks * 32 + q * 8];
      bf16x8 a1 = *(const bf16x8*)&As[cur][m0 + 16 + lm][ks * 32 + q * 8];
      bf16x8 b0 = *(const bf16x8*)&Bs[cur][n0 + lm]     [ks * 32 + q * 8];
      bf16x8 b1 = *(const bf16x8*)&Bs[cur][n0 + 16 + lm][ks * 32 + q * 8];
      acc[0][0] = __builtin_amdgcn_mfma_f32_16x16x32_bf16(a0, b0, acc[0][0], 0, 0, 0);
      acc[0][1] = __builtin_amdgcn_mfma_f32_16x16x32_bf16(a0, b1, acc[0][1], 0, 0, 0);
      acc[1][0] = __builtin_amdgcn_mfma_f32_16x16x32_bf16(a1, b0, acc[1][0], 0, 0, 0);
      acc[1][1] = __builtin_amdgcn_mfma_f32_16x16x32_bf16(a1, b1, acc[1][1], 0, 0, 0);
    }
  }

  // epilogue: C/D layout col=lane&15, row=q*4+r; store bf16
  #pragma unroll
  for (int ti = 0; ti < 2; ++ti) {
    #pragma unroll
    for (int tj = 0; tj < 2; ++tj) {
      int col = col0 + n0 + tj * 16 + lm;
      if (col >= NLOG) continue;
      int pc = (col < H1_) ? col : col + (VOFFB - H1_);
      #pragma unroll
      for (int r = 0; r < 4; ++r) {
        int row = row0 + m0 + ti * 16 + q * 4 + r;
        Yb[(size_t)row * YSB + pc] = f2bf(acc[ti][tj][r]);
      }
    }
  }
}

// ---------------------------------------------------------------------------
// tile decode: T -> (ti, d); tile = i in [4ti,4ti+4) x j in [4(ti+d),+4)
// counts: ti<24 -> 9 d's; ti in [24,32) -> 32-ti d's. Total 252.
// ---------------------------------------------------------------------------
__device__ inline void tile_decode(int T, int& ti, int& d) {
  if (T < 216) { ti = T / 9; d = T - ti * 9; }
  else {
    int m = T - 216; int r = 24, w = 8;
    while (m >= w) { m -= w; --w; ++r; }
    ti = r; d = m;
  }
}
// row-major rank of an in-band pair (i,j)
__device__ inline int pair_rank(int i, int j) {
  return (i < 99) ? i * 30 + (j - i)
                  : NPAIRS - (128 - i) * (129 - i) / 2 + (j - i);
}

// ---------------------------------------------------------------------------
// Kernel 2 (MFMA, LDS-free, 4x4-tiled): wave = one 4x4 (i,j) tile (16 pairs)
// x 48 outs. Lane lm -> pair (i0+(lm&3), j0+(lm>>2)): U and V loads each hit
// only 4 distinct rows per 16-lane group (vs 2+16 row-major). B-frags read
// from Bswz in fragment order: one contiguous 1KB wave-load per frag.
// Out-of-band lanes compute finite garbage, masked at store.
// ---------------------------------------------------------------------------
__global__ __launch_bounds__(256) void pair_mfma(
    const unsigned short* __restrict__ Yb, const int* __restrict__ spans,
    const unsigned short* __restrict__ Bswz, const float* __restrict__ Cv,
    const float* __restrict__ b2, float* __restrict__ out)
{
  const int tid = threadIdx.x;
  const int bb = blockIdx.y;
  const int lane = tid & 63, w = tid >> 6;
  const int lm = lane & 15, q = lane >> 4;

  int ti, d;
  tile_decode(blockIdx.x * 4 + w, ti, d);      // 63*4 = 252 tiles exactly
  const int i0 = ti * 4, j0 = (ti + d) * 4;

  const int ai = i0 + (lm & 3);
  const int aj = j0 + (lm >> 2);
  const int s = spans[2 * bb], e = spans[2 * bb + 1];
  const int ind = (ai == s && aj == e) ? 2 : ((ai >= s && aj <= e) ? 1 : 0);

  const unsigned short* uptr = Yb + (size_t)(bb * L_ + ai) * YSB + q * 8;
  const unsigned short* vptr = Yb + (size_t)(bb * L_ + aj) * YSB + VOFFB + q * 8;
  const float* cptr = Cv + ind * KPAD + q * 8;
  const unsigned short* bbase = Bswz + lane * 8;

  f32x4 acc0 = {}, acc1 = {}, acc2 = {};

  #pragma unroll 5
  for (int ks = 0; ks < NKS; ++ks) {
    const int ko = ks * 32;
    u16x8 uu = *(const u16x8*)(uptr + ko);
    u16x8 vv = *(const u16x8*)(vptr + ko);
    float4 c0 = *(const float4*)(cptr + ko);
    float4 c1 = *(const float4*)(cptr + ko + 4);
    float h0 = fmaxf(bf2f(uu[0]) + bf2f(vv[0]) + c0.x, 0.f);
    float h1 = fmaxf(bf2f(uu[1]) + bf2f(vv[1]) + c0.y, 0.f);
    float h2 = fmaxf(bf2f(uu[2]) + bf2f(vv[2]) + c0.z, 0.f);
    float h3 = fmaxf(bf2f(uu[3]) + bf2f(vv[3]) + c0.w, 0.f);
    float h4 = fmaxf(bf2f(uu[4]) + bf2f(vv[4]) + c1.x, 0.f);
    float h5 = fmaxf(bf2f(uu[5]) + bf2f(vv[5]) + c1.y, 0.f);
    float h6 = fmaxf(bf2f(uu[6]) + bf2f(vv[6]) + c1.z, 0.f);
    float h7 = fmaxf(bf2f(uu[7]) + bf2f(vv[7]) + c1.w, 0.f);
    u32x4 hp;
    hp[0] = pack_bf16(h0, h1);
    hp[1] = pack_bf16(h2, h3);
    hp[2] = pack_bf16(h4, h5);
    hp[3] = pack_bf16(h6, h7);
    bf16x8 a = __builtin_bit_cast(bf16x8, hp);
    bf16x8 bf0 = *(const bf16x8*)(bbase + (size_t)(ks * 3 + 0) * 512);
    bf16x8 bf1 = *(const bf16x8*)(bbase + (size_t)(ks * 3 + 1) * 512);
    bf16x8 bf2v = *(const bf16x8*)(bbase + (size_t)(ks * 3 + 2) * 512);
    acc0 = __builtin_amdgcn_mfma_f32_16x16x32_bf16(a, bf0, acc0, 0, 0, 0);
    acc1 = __builtin_amdgcn_mfma_f32_16x16x32_bf16(a, bf1, acc1, 0, 0, 0);
    acc2 = __builtin_amdgcn_mfma_f32_16x16x32_bf16(a, bf2v, acc2, 0, 0, 0);
  }

  // epilogue: C/D row p=4q+r -> pair (i0+r, j0+q), col lm.
  const float b2v0 = b2[lm];
  const float b2v1 = b2[16 + lm];
  const float b2v2 = (lm < 8) ? b2[32 + lm] : 0.f;
  const int oi = i0 /*+ r below*/, oj = j0 + q;

  #pragma unroll
  for (int r = 0; r < 4; ++r) {
    float l0 = acc0[r] + b2v0;
    float l1 = acc1[r] + b2v1;
    float l2 = (lm < 8) ? (acc2[r] + b2v2) : -INFINITY;
    float mx = fmaxf(fmaxf(l0, l1), l2);
    mx = fmaxf(mx, __shfl_xor(mx, 1));
    mx = fmaxf(mx, __shfl_xor(mx, 2));
    mx = fmaxf(mx, __shfl_xor(mx, 4));
    mx = fmaxf(mx, __shfl_xor(mx, 8));
    float sm = expf(l0 - mx) + expf(l1 - mx) + ((lm < 8) ? expf(l2 - mx) : 0.f);
    sm += __shfl_xor(sm, 1);
    sm += __shfl_xor(sm, 2);
    sm += __shfl_xor(sm, 4);
    sm += __shfl_xor(sm, 8);
    float lsd = mx + logf(sm);

    int pi_ = oi + r, pj_ = oj;
    if (pj_ >= pi_ && (pj_ - pi_) < 30) {       // in-band (pj_ < 128 guaranteed)
      float* op = out + ((size_t)bb * NPAIRS + pair_rank(pi_, pj_)) * OUT_;
      op[lm]      = l0 - lsd;
      op[16 + lm] = l1 - lsd;
      if (lm < 8) op[32 + lm] = l2 - lsd;
    }
  }
}

// ---------------------------------------------------------------------------
extern "C" void kernel_launch(void* const* d_in, const int* in_sizes, int n_in,
                              void* d_out, int out_size, void* d_ws, size_t ws_size,
                              hipStream_t stream) {
  const float* hidden = (const float*)d_in[0];   // (16,129,768) f32
  const int*   spans  = (const int*)d_in[1];     // (16,2) i32
  const float* W1 = (const float*)d_in[4];       // (1537,770) f32
  const float* b1 = (const float*)d_in[5];       // (770,)
  const float* W2 = (const float*)d_in[6];       // (770,40)
  const float* b2 = (const float*)d_in[7];       // (40,)
  float* out = (float*)d_out;                    // (16,3405,40) f32

  // workspace layout (256B-aligned slabs). Yb has one spare row: pair_mfma's
  // V-tail k-reads on the last row overrun by <48 shorts into poisoned-but-
  // finite space (killed by Bswz zero-padding).
  char* base = (char*)d_ws;
  size_t off = 0;
  auto take = [&](size_t bytes) {
    char* p = base + off;
    off = (off + bytes + 255) & ~(size_t)255;
    return p;
  };
  unsigned short* Yb   = (unsigned short*)take((size_t)2049 * YSB * 2);     // 6.36 MB
  unsigned short* Xb   = (unsigned short*)take((size_t)2048 * D_ * 2);      // 3.15 MB
  unsigned short* W1T  = (unsigned short*)take((size_t)W1TROWS * D_ * 2);   // 2.46 MB
  unsigned short* Bswz = (unsigned short*)take((size_t)NKS * 3 * 512 * 2);  // 76.8 KB
  float*          Cv   = (float*)take((size_t)3 * KPAD * 4);                // 9.6 KB

  prep_all<<<dim3(NB_X + NB_W + NB_T), 256, 0, stream>>>(
      hidden, W1, b1, W2, Xb, W1T, Bswz, Cv);
  gemm1_mfma<<<dim3(25, 32), 256, 0, stream>>>(Xb, W1T, Yb);
  pair_mfma<<<dim3(63, B_), 256, 0, stream>>>(Yb, spans, Bswz, Cv, b2, out);
}